// Round 1
// baseline (6606.723 us; speedup 1.0000x reference)
//
#include <hip/hip_runtime.h>

// LIF layer: Wx = x @ W^T  (f64 accumulate), then sequential scan over T.
// B=64, T=1000, I=1024, H=1024. Chunked over B (Bc=8) so workspace = 65.5 MB.

#define TM 64
#define TN 64
#define TK 32

__global__ __launch_bounds__(256) void gemm_f64_kernel(
    const float* __restrict__ A,   // [M,K] row-major (x chunk)
    const float* __restrict__ B,   // [N,K] row-major (W, i.e. B^T layout)
    double* __restrict__ C,        // [M,N] f64 out
    int M, int N, int K)
{
    // +1 pad: staging writes <=2-way bank alias (free), fragment reads conflict-free
    __shared__ double As[TK][TM + 1];
    __shared__ double Bs[TK][TN + 1];

    const int tid = threadIdx.x;
    const int tx = tid & 15;        // col group 0..15
    const int ty = tid >> 4;        // row group 0..15
    const int tm = blockIdx.y * TM;
    const int tn = blockIdx.x * TN;

    // staging: thread loads float4 at (row r / r+32, k-quad kq)
    const int kq = (tid & 7) * 4;   // 0,4,..,28
    const int r  = tid >> 3;        // 0..31

    double acc[4][4];
    #pragma unroll
    for (int i = 0; i < 4; i++)
        #pragma unroll
        for (int j = 0; j < 4; j++) acc[i][j] = 0.0;

    const float* Arow0 = A + (size_t)(tm + r)      * K;
    const float* Arow1 = A + (size_t)(tm + r + 32) * K;
    const float* Brow0 = B + (size_t)(tn + r)      * K;
    const float* Brow1 = B + (size_t)(tn + r + 32) * K;

    for (int k0 = 0; k0 < K; k0 += TK) {
        const float4 a0 = *(const float4*)(Arow0 + k0 + kq);
        const float4 a1 = *(const float4*)(Arow1 + k0 + kq);
        const float4 b0 = *(const float4*)(Brow0 + k0 + kq);
        const float4 b1 = *(const float4*)(Brow1 + k0 + kq);

        __syncthreads();   // previous iteration's LDS reads complete

        As[kq + 0][r] = (double)a0.x; As[kq + 1][r] = (double)a0.y;
        As[kq + 2][r] = (double)a0.z; As[kq + 3][r] = (double)a0.w;
        As[kq + 0][r + 32] = (double)a1.x; As[kq + 1][r + 32] = (double)a1.y;
        As[kq + 2][r + 32] = (double)a1.z; As[kq + 3][r + 32] = (double)a1.w;
        Bs[kq + 0][r] = (double)b0.x; Bs[kq + 1][r] = (double)b0.y;
        Bs[kq + 2][r] = (double)b0.z; Bs[kq + 3][r] = (double)b0.w;
        Bs[kq + 0][r + 32] = (double)b1.x; Bs[kq + 1][r + 32] = (double)b1.y;
        Bs[kq + 2][r + 32] = (double)b1.z; Bs[kq + 3][r + 32] = (double)b1.w;

        __syncthreads();

        #pragma unroll
        for (int kk = 0; kk < TK; kk++) {
            double av[4], bv[4];
            #pragma unroll
            for (int i = 0; i < 4; i++) av[i] = As[kk][ty + 16 * i];
            #pragma unroll
            for (int j = 0; j < 4; j++) bv[j] = Bs[kk][tx + 16 * j];
            #pragma unroll
            for (int i = 0; i < 4; i++)
                #pragma unroll
                for (int j = 0; j < 4; j++)
                    acc[i][j] = fma(av[i], bv[j], acc[i][j]);
        }
    }

    #pragma unroll
    for (int i = 0; i < 4; i++) {
        const size_t row = (size_t)(tm + ty + 16 * i) * N;
        #pragma unroll
        for (int j = 0; j < 4; j++)
            C[row + tn + tx + 16 * j] = acc[i][j];
    }
}

__global__ __launch_bounds__(256) void lif_scan_kernel(
    const double* __restrict__ Wx,  // [Bc, T, H] chunk
    const float* __restrict__ alpha,
    const float* __restrict__ u0,
    const float* __restrict__ s0,
    float* __restrict__ out,        // full [B, T, H]
    int b0, int T, int H)
{
    const int idx = blockIdx.x * blockDim.x + threadIdx.x;   // 0..Bc*H-1
    const int h  = idx & (1024 - 1);   // H = 1024
    const int bl = idx >> 10;
    const int b  = b0 + bl;

    const double AMIN = 0.8187307530779818;   // exp(-1/5), repr round-trips exactly
    const double AMAX = 0.9607894391523232;   // exp(-1/25)
    double a = (double)alpha[h];
    a = fmin(fmax(a, AMIN), AMAX);
    const double oma = 1.0 - a;

    double u = (double)u0[(size_t)b * H + h];
    double s = (double)s0[(size_t)b * H + h];   // continuous init, per reference

    const double* wp = Wx + (size_t)bl * T * H + h;
    float* op = out + (size_t)b * T * H + h;

    for (int t = 0; t < T; ++t) {
        const double wx = wp[(size_t)t * H];
        u = a * (u - s) + oma * wx;
        s = (u - 1.0 > 0.0) ? 1.0 : 0.0;
        op[(size_t)t * H] = (float)s;
    }
}

extern "C" void kernel_launch(void* const* d_in, const int* in_sizes, int n_in,
                              void* d_out, int out_size, void* d_ws, size_t ws_size,
                              hipStream_t stream) {
    const float* x     = (const float*)d_in[0];   // [64,1000,1024]
    const float* W     = (const float*)d_in[1];   // [1024,1024]
    const float* alpha = (const float*)d_in[2];   // [1024]
    const float* u0    = (const float*)d_in[3];   // [64,1024]
    const float* s0    = (const float*)d_in[4];   // [64,1024]
    float* out = (float*)d_out;                   // [64,1000,1024] f32
    double* wx = (double*)d_ws;                   // [8,1000,1024] f64 = 65.5 MB

    const int Bt = 64, T = 1000, I = 1024, H = 1024;
    const int Bc = 8;   // batch chunk -> ws = Bc*T*H*8 bytes

    for (int b0 = 0; b0 < Bt; b0 += Bc) {
        dim3 grid(H / TN, (Bc * T) / TM);   // 16 x 125
        gemm_f64_kernel<<<grid, 256, 0, stream>>>(
            x + (size_t)b0 * T * I, W, wx, Bc * T, H, I);
        lif_scan_kernel<<<(Bc * H) / 256, 256, 0, stream>>>(
            wx, alpha, u0, s0, out, b0, T, H);
    }
}

// Round 2
// 2996.254 us; speedup vs baseline: 2.2050x; 2.2050x over previous
//
#include <hip/hip_runtime.h>

// LIF layer: Wx = x @ W^T (f64 accumulate), then sequential scan over T.
// B=64, T=1000, I=1024, H=1024.
// R2: 128x128 GEMM tile w/ 8x8 f64 acc per thread (8:1 FMA:LDS-read ratio),
//     scan with 8-deep load prefetch + adaptive batch chunking by ws_size.

#define TM 128
#define TN 128
#define TK 16
#define PAD 2   // keeps row stride even -> 16B-aligned b128 LDS reads

__global__ __launch_bounds__(256, 2) void gemm_f64_kernel(
    const float* __restrict__ A,   // [M,K] row-major (x chunk)
    const float* __restrict__ B,   // [N,K] row-major (W)
    double* __restrict__ C,        // [M,N] f64
    int M, int N, int K)
{
    __shared__ double As[TK][TM + PAD];
    __shared__ double Bs[TK][TN + PAD];

    const int tid = threadIdx.x;
    const int tx = tid & 15;
    const int ty = tid >> 4;
    const int tm = blockIdx.y * TM;
    const int tn = blockIdx.x * TN;

    // staging: 4 lanes cover one row's 16 k-values (64B contiguous per 4 lanes)
    const int kq = (tid & 3) * 4;   // 0,4,8,12
    const int r  = tid >> 2;        // 0..63

    double acc[8][8];
    #pragma unroll
    for (int i = 0; i < 8; i++)
        #pragma unroll
        for (int j = 0; j < 8; j++) acc[i][j] = 0.0;

    const int ar0 = min(tm + r,      M - 1);   // tail-block guard (M=8000 case)
    const int ar1 = min(tm + r + 64, M - 1);
    const float* Ap0 = A + (size_t)ar0 * K + kq;
    const float* Ap1 = A + (size_t)ar1 * K + kq;
    const float* Bp0 = B + (size_t)(tn + r)      * K + kq;
    const float* Bp1 = B + (size_t)(tn + r + 64) * K + kq;

    for (int k0 = 0; k0 < K; k0 += TK) {
        const float4 a0 = *(const float4*)(Ap0 + k0);
        const float4 a1 = *(const float4*)(Ap1 + k0);
        const float4 b0 = *(const float4*)(Bp0 + k0);
        const float4 b1 = *(const float4*)(Bp1 + k0);

        __syncthreads();   // previous iteration's LDS reads complete

        As[kq + 0][r] = (double)a0.x; As[kq + 1][r] = (double)a0.y;
        As[kq + 2][r] = (double)a0.z; As[kq + 3][r] = (double)a0.w;
        As[kq + 0][r + 64] = (double)a1.x; As[kq + 1][r + 64] = (double)a1.y;
        As[kq + 2][r + 64] = (double)a1.z; As[kq + 3][r + 64] = (double)a1.w;
        Bs[kq + 0][r] = (double)b0.x; Bs[kq + 1][r] = (double)b0.y;
        Bs[kq + 2][r] = (double)b0.z; Bs[kq + 3][r] = (double)b0.w;
        Bs[kq + 0][r + 64] = (double)b1.x; Bs[kq + 1][r + 64] = (double)b1.y;
        Bs[kq + 2][r + 64] = (double)b1.z; Bs[kq + 3][r + 64] = (double)b1.w;

        __syncthreads();

        #pragma unroll
        for (int kk = 0; kk < TK; kk++) {
            double av[8], bv[8];
            #pragma unroll
            for (int i = 0; i < 4; i++) {
                av[2 * i]     = As[kk][2 * ty + 32 * i];      // adjacent pair ->
                av[2 * i + 1] = As[kk][2 * ty + 32 * i + 1];  //   ds_read_b128
            }
            #pragma unroll
            for (int j = 0; j < 4; j++) {
                bv[2 * j]     = Bs[kk][2 * tx + 32 * j];
                bv[2 * j + 1] = Bs[kk][2 * tx + 32 * j + 1];
            }
            #pragma unroll
            for (int i = 0; i < 8; i++)
                #pragma unroll
                for (int j = 0; j < 8; j++)
                    acc[i][j] = fma(av[i], bv[j], acc[i][j]);
        }
    }

    #pragma unroll
    for (int i = 0; i < 8; i++) {
        const int m = tm + 2 * ty + 32 * (i >> 1) + (i & 1);
        if (m < M) {
            double* Cr = C + (size_t)m * N + tn;
            #pragma unroll
            for (int j = 0; j < 8; j++)
                Cr[2 * tx + 32 * (j >> 1) + (j & 1)] = acc[i][j];
        }
    }
}

__global__ __launch_bounds__(256) void lif_scan_kernel(
    const double* __restrict__ Wx,  // [Bc, T, H] chunk
    const float* __restrict__ alpha,
    const float* __restrict__ u0,
    const float* __restrict__ s0,
    float* __restrict__ out,        // full [B, T, H]
    int b0, int T, int H)
{
    const int idx = blockIdx.x * blockDim.x + threadIdx.x;   // 0..Bc*H-1
    const int h  = idx & 1023;      // H = 1024
    const int bl = idx >> 10;
    const int b  = b0 + bl;

    const double AMIN = 0.8187307530779818;   // exp(-1/5)
    const double AMAX = 0.9607894391523232;   // exp(-1/25)
    double a = (double)alpha[h];
    a = fmin(fmax(a, AMIN), AMAX);
    const double oma = 1.0 - a;

    double u = (double)u0[(size_t)b * H + h];
    double s = (double)s0[(size_t)b * H + h];

    const double* wp = Wx + (size_t)bl * T * H + h;
    float* op = out + (size_t)b * T * H + h;

    // 8-deep prefetch: 8 independent loads in flight while computing the
    // previous group of 8 dependent recurrence steps. T=1000 = 125*8.
    double v[8];
    #pragma unroll
    for (int p = 0; p < 8; p++) v[p] = wp[(size_t)p * H];

    for (int t0 = 0; t0 < T; t0 += 8) {
        double nv[8];
        const bool more = (t0 + 8) < T;
        const double* wn = wp + (size_t)(t0 + 8) * H;
        #pragma unroll
        for (int p = 0; p < 8; p++) nv[p] = more ? wn[(size_t)p * H] : 0.0;

        #pragma unroll
        for (int p = 0; p < 8; p++) {
            u = a * (u - s) + oma * v[p];           // keep exact ref op order
            s = (u - 1.0 > 0.0) ? 1.0 : 0.0;
            op[(size_t)(t0 + p) * H] = (float)s;
        }
        #pragma unroll
        for (int p = 0; p < 8; p++) v[p] = nv[p];
    }
}

extern "C" void kernel_launch(void* const* d_in, const int* in_sizes, int n_in,
                              void* d_out, int out_size, void* d_ws, size_t ws_size,
                              hipStream_t stream) {
    const float* x     = (const float*)d_in[0];   // [64,1000,1024]
    const float* W     = (const float*)d_in[1];   // [1024,1024]
    const float* alpha = (const float*)d_in[2];   // [1024]
    const float* u0    = (const float*)d_in[3];   // [64,1024]
    const float* s0    = (const float*)d_in[4];   // [64,1024]
    float* out = (float*)d_out;                   // [64,1000,1024] f32
    double* wx = (double*)d_ws;

    const int Bt = 64, T = 1000, I = 1024, H = 1024;

    // Adaptive chunk: largest Bc whose f64 Wx chunk fits the workspace.
    const size_t per_batch = (size_t)T * H * sizeof(double);   // 8.192 MB
    int Bc = 1;
    {
        const int cands[7] = {64, 32, 16, 8, 4, 2, 1};
        for (int c = 0; c < 7; c++) {
            if ((size_t)cands[c] * per_batch <= ws_size) { Bc = cands[c]; break; }
        }
    }

    for (int b0 = 0; b0 < Bt; b0 += Bc) {
        const int M = Bc * T;
        dim3 grid(H / TN, (M + TM - 1) / TM);
        gemm_f64_kernel<<<grid, 256, 0, stream>>>(
            x + (size_t)b0 * T * I, W, wx, M, H, I);
        lif_scan_kernel<<<(Bc * H) / 256, 256, 0, stream>>>(
            wx, alpha, u0, s0, out, b0, T, H);
    }
}